// Round 7
// baseline (107.306 us; speedup 1.0000x reference)
//
#include <hip/hip_runtime.h>

#define WSTRIDE 8704   // padded row stride for wab (shifted layout, max idx 8452)

__device__ __forceinline__ float lrelu(float x) { return x > 0.0f ? x : 0.01f * x; }

// h0T[j][b] = lrelu(sum_l z[b][l]*W0[l][j] + b0[j]); one block per j, lane = b
__global__ __launch_bounds__(128) void h0T_kernel(const float* __restrict__ z,
                                                  const float* __restrict__ W,
                                                  const float* __restrict__ bias,
                                                  float* __restrict__ h0T) {
    int j = blockIdx.x;          // 0..511
    int b = threadIdx.x;         // 0..127
    float zr[16];
    *(float4*)&zr[0]  = *(const float4*)&z[b * 16 + 0];
    *(float4*)&zr[4]  = *(const float4*)&z[b * 16 + 4];
    *(float4*)&zr[8]  = *(const float4*)&z[b * 16 + 8];
    *(float4*)&zr[12] = *(const float4*)&z[b * 16 + 12];
    float acc = bias[j];
#pragma unroll
    for (int l = 0; l < 16; ++l) acc = fmaf(zr[l], W[l * 512 + j], acc);
    h0T[j * 128 + b] = lrelu(acc);
}

// OT[j][b] = lrelu(sum_k At[k][b]*W[k][j] + bias[j]); At is [512][128]
// 512 thr = 8 k-split waves; tile 64 j x 4 b; grid 256 = 8 jt x 32 bt.
// A operand via VMEM broadcast loads (laundered wave id keeps it off SMEM).
__global__ __launch_bounds__(512, 2) void gemmT_kernel(const float* __restrict__ At,
                                                       const float* __restrict__ W,
                                                       const float* __restrict__ bias,
                                                       float* __restrict__ OT) {
    __shared__ float red[8][64][5];
    int jt = blockIdx.x & 7;
    int bt = blockIdx.x >> 3;          // 0..31
    int tid = threadIdx.x;
    int lane = tid & 63;
    int widv = tid >> 6;               // 0..7
    asm volatile("v_mov_b32 %0, %0" : "+v"(widv));  // block scalarization of A loads
    int wid = __builtin_amdgcn_readfirstlane(tid >> 6);
    int b0 = bt * 4;
    int j = jt * 64 + lane;
    int k0 = widv * 64;
    const float* __restrict__ Ap = At + (size_t)k0 * 128 + b0;
    const float* __restrict__ Wp = W + (size_t)k0 * 512 + j;
    float acc[4] = {};
#pragma unroll 8
    for (int kk = 0; kk < 64; ++kk) {
        float4 a = *(const float4*)(Ap + (size_t)kk * 128);  // VMEM broadcast
        float w = Wp[(size_t)kk * 512];                      // coalesced dword
        acc[0] = fmaf(a.x, w, acc[0]);
        acc[1] = fmaf(a.y, w, acc[1]);
        acc[2] = fmaf(a.z, w, acc[2]);
        acc[3] = fmaf(a.w, w, acc[3]);
    }
#pragma unroll
    for (int i = 0; i < 4; ++i) red[wid][lane][i] = acc[i];
    __syncthreads();
    if (tid < 256) {
        int jj = tid >> 2;             // 0..63
        int bb = tid & 3;
        float s = 0.f;
#pragma unroll
        for (int w = 0; w < 8; ++w) s += red[w][jj][bb];
        int jg = jt * 64 + jj;
        OT[jg * 128 + b0 + bb] = lrelu(s + bias[jg]);
    }
}

// wab[b][dest(j)] = sum_k At[k][b]*hWo[k][j] + hbo[j]; dest(j)=j+(j>=65?3:0)
// (+3 shift 16B-aligns W1/W2 rows for the decoder's float4 loads)
// tile 128 j x 16 b, k-split 4 (256 thr). acc[16][2]=32 regs; 4-stage register
// pipeline; A via VMEM broadcast; in-block LDS reduce writes final wab.
// Grid 536 = 67 jt x 8 bt, XCD-grouped (blocks sharing jt land on one XCD).
__global__ __launch_bounds__(256, 2) void wabT_kernel(const float* __restrict__ At,
                                                      const float* __restrict__ W,
                                                      const float* __restrict__ bias,
                                                      float* __restrict__ wab) {
    __shared__ float red[4][64][33];   // 33.8 KB, stride 33 -> conflict-free
    int tid = threadIdx.x;
    int lane = tid & 63;
    int widv = tid >> 6;               // 0..3
    asm volatile("v_mov_b32 %0, %0" : "+v"(widv));  // keep A loads on vector path
    int wid = __builtin_amdgcn_readfirstlane(tid >> 6);
    int v = (blockIdx.x & 7) * 67 + (blockIdx.x >> 3);  // 0..535, XCD-grouped
    int jt = v >> 3;                   // 0..66
    int bt = v & 7;                    // 0..7
    int b0 = bt * 16;
    int j0r = jt * 128 + lane * 2;
    int j0 = j0r < 8448 ? j0r : 8448;  // clamp keeps float2 loads in-bounds & aligned
    int k0 = widv * 128;
    const float* __restrict__ Ap = At + (size_t)k0 * 128 + b0;
    const float* __restrict__ Wp = W + (size_t)k0 * 8450 + j0;
    float acc[16][2];
#pragma unroll
    for (int i = 0; i < 16; ++i) { acc[i][0] = 0.f; acc[i][1] = 0.f; }

#define LDK(A, Wv, kk) do {                                     \
        const float* ap_ = Ap + (size_t)(kk) * 128;             \
        *(float4*)&A[0]  = *(const float4*)(ap_ + 0);           \
        *(float4*)&A[4]  = *(const float4*)(ap_ + 4);           \
        *(float4*)&A[8]  = *(const float4*)(ap_ + 8);           \
        *(float4*)&A[12] = *(const float4*)(ap_ + 12);          \
        Wv = *(const float2*)(Wp + (size_t)(kk) * 8450);        \
    } while (0)
#define FMAK(A, Wv) do {                                        \
        _Pragma("unroll")                                       \
        for (int i_ = 0; i_ < 16; ++i_) {                       \
            acc[i_][0] = fmaf(A[i_], Wv.x, acc[i_][0]);         \
            acc[i_][1] = fmaf(A[i_], Wv.y, acc[i_][1]);         \
        }                                                       \
    } while (0)

    float s0[16], s1[16], s2[16], s3[16];
    float2 u0, u1, u2, u3;
    LDK(s0, u0, 0); LDK(s1, u1, 1); LDK(s2, u2, 2); LDK(s3, u3, 3);
    for (int base = 0; base < 124; base += 4) {   // base = 0,4,...,120
        FMAK(s0, u0); LDK(s0, u0, base + 4);
        FMAK(s1, u1); LDK(s1, u1, base + 5);
        FMAK(s2, u2); LDK(s2, u2, base + 6);
        FMAK(s3, u3); LDK(s3, u3, base + 7);
    }
    FMAK(s0, u0); FMAK(s1, u1); FMAK(s2, u2); FMAK(s3, u3);  // kk 124..127
#undef LDK
#undef FMAK

#pragma unroll
    for (int i = 0; i < 16; ++i) {
        red[wid][lane][i * 2 + 0] = acc[i][0];
        red[wid][lane][i * 2 + 1] = acc[i][1];
    }
    __syncthreads();
    // reduce: thread t -> ls = t&63, q = t>>6 owns idx q*8..q*8+7 (idx = bb*2+par)
    int q = tid >> 6;
    int ls = tid & 63;
    int jb = jt * 128 + ls * 2;
#pragma unroll
    for (int m = 0; m < 8; ++m) {
        int idx = q * 8 + m;
        float s = red[0][ls][idx] + red[1][ls][idx]
                + red[2][ls][idx] + red[3][ls][idx];
        int bb = b0 + (idx >> 1);
        int jlog = jb + (idx & 1);
        if (jlog < 8450)
            wab[(size_t)bb * WSTRIDE + jlog + (jlog >= 65 ? 3 : 0)] = s + bias[jlog];
    }
}

// Decoder. wab row layout (post-shift): w0[0:64], b0[64], pad[65:68),
// W1[68:4164), b1[4164:4228), W2[4228:8324), b2[8324:8388), w3[8388:8452), b3[8452].
// lane = g, jq = wave's 16-j slice. W read straight from global (uniform-address
// vector loads -> VMEM broadcast, vmcnt-pipelined; LDS only holds h state).
__global__ __launch_bounds__(256) void decoder_kernel(const float* __restrict__ wab,
                                                      const float* __restrict__ logP,
                                                      float* __restrict__ out) {
    __shared__ float hX[64 * 65];
    __shared__ float hY[64 * 65];
    __shared__ float red[4][68];
    int b  = blockIdx.x >> 1;
    int gh = blockIdx.x & 1;
    int tid = threadIdx.x;
    int lane = tid & 63;
    int jq = (tid >> 6) * 16;   // NOT readfirstlane: keeps W loads on the vector path
    int g = gh * 64 + lane;
    bool act = g < 100;
    const float* __restrict__ row = wab + (size_t)b * WSTRIDE;
    float x0 = act ? logP[b * 100 + g] * (1.0f / 3.0f) : 0.0f;
    float c0 = row[64];
#pragma unroll
    for (int t = 0; t < 16; ++t)
        hX[(jq + t) * 65 + lane] = __sinf(30.0f * fmaf(x0, row[jq + t], c0));
    __syncthreads();
    // layer 1: hY[j][g] = sin(sum_i hX[i][g]*W1[i][j] + b1[j])
    {
        float a[16];
#pragma unroll
        for (int t = 0; t < 16; ++t) a[t] = row[4164 + jq + t];
#pragma unroll 4
        for (int i = 0; i < 64; ++i) {
            float hi = hX[i * 65 + lane];
            const float* wr = row + 68 + i * 64 + jq;   // 16B aligned
            float4 w0 = *(const float4*)&wr[0];
            float4 w1 = *(const float4*)&wr[4];
            float4 w2 = *(const float4*)&wr[8];
            float4 w3 = *(const float4*)&wr[12];
            a[0]  = fmaf(hi, w0.x, a[0]);  a[1]  = fmaf(hi, w0.y, a[1]);
            a[2]  = fmaf(hi, w0.z, a[2]);  a[3]  = fmaf(hi, w0.w, a[3]);
            a[4]  = fmaf(hi, w1.x, a[4]);  a[5]  = fmaf(hi, w1.y, a[5]);
            a[6]  = fmaf(hi, w1.z, a[6]);  a[7]  = fmaf(hi, w1.w, a[7]);
            a[8]  = fmaf(hi, w2.x, a[8]);  a[9]  = fmaf(hi, w2.y, a[9]);
            a[10] = fmaf(hi, w2.z, a[10]); a[11] = fmaf(hi, w2.w, a[11]);
            a[12] = fmaf(hi, w3.x, a[12]); a[13] = fmaf(hi, w3.y, a[13]);
            a[14] = fmaf(hi, w3.z, a[14]); a[15] = fmaf(hi, w3.w, a[15]);
        }
#pragma unroll
        for (int t = 0; t < 16; ++t) hY[(jq + t) * 65 + lane] = __sinf(a[t]);
    }
    __syncthreads();
    // layer 2: hX[j][g] = sin(sum_i hY[i][g]*W2[i][j] + b2[j])
    {
        float a[16];
#pragma unroll
        for (int t = 0; t < 16; ++t) a[t] = row[8324 + jq + t];
#pragma unroll 4
        for (int i = 0; i < 64; ++i) {
            float hi = hY[i * 65 + lane];
            const float* wr = row + 4228 + i * 64 + jq;
            float4 w0 = *(const float4*)&wr[0];
            float4 w1 = *(const float4*)&wr[4];
            float4 w2 = *(const float4*)&wr[8];
            float4 w3 = *(const float4*)&wr[12];
            a[0]  = fmaf(hi, w0.x, a[0]);  a[1]  = fmaf(hi, w0.y, a[1]);
            a[2]  = fmaf(hi, w0.z, a[2]);  a[3]  = fmaf(hi, w0.w, a[3]);
            a[4]  = fmaf(hi, w1.x, a[4]);  a[5]  = fmaf(hi, w1.y, a[5]);
            a[6]  = fmaf(hi, w1.z, a[6]);  a[7]  = fmaf(hi, w1.w, a[7]);
            a[8]  = fmaf(hi, w2.x, a[8]);  a[9]  = fmaf(hi, w2.y, a[9]);
            a[10] = fmaf(hi, w2.z, a[10]); a[11] = fmaf(hi, w2.w, a[11]);
            a[12] = fmaf(hi, w3.x, a[12]); a[13] = fmaf(hi, w3.y, a[13]);
            a[14] = fmaf(hi, w3.z, a[14]); a[15] = fmaf(hi, w3.w, a[15]);
        }
#pragma unroll
        for (int t = 0; t < 16; ++t) hX[(jq + t) * 65 + lane] = __sinf(a[t]);
    }
    __syncthreads();
    // layer 3
    float p = 0.f;
#pragma unroll
    for (int t = 0; t < 16; ++t)
        p = fmaf(hX[(jq + t) * 65 + lane], row[8388 + jq + t], p);
    red[tid >> 6][lane] = p;
    __syncthreads();
    if (tid < 64 && act) {
        float s = red[0][lane] + red[1][lane] + red[2][lane] + red[3][lane] + row[8452];
        out[b * 100 + g] = fmaf(s, 500.0f, 1500.0f);
    }
}

extern "C" void kernel_launch(void* const* d_in, const int* in_sizes, int n_in,
                              void* d_out, int out_size, void* d_ws, size_t ws_size,
                              hipStream_t stream) {
    const float* z    = (const float*)d_in[0];
    const float* logP = (const float*)d_in[1];
    const float* hW0  = (const float*)d_in[2];
    const float* hb0  = (const float*)d_in[3];
    const float* hW1  = (const float*)d_in[4];
    const float* hb1  = (const float*)d_in[5];
    const float* hW2  = (const float*)d_in[6];
    const float* hb2  = (const float*)d_in[7];
    const float* hWo  = (const float*)d_in[8];
    const float* hbo  = (const float*)d_in[9];
    float* out = (float*)d_out;

    float* wab = (float*)d_ws;               // 128*8704 floats (4.46 MB)
    float* h0T = wab + 128 * WSTRIDE;        // 512*128 floats (transposed)
    float* h1T = h0T + 512 * 128;
    float* h2T = h1T + 512 * 128;            // total ~5.25 MB

    h0T_kernel<<<512, 128, 0, stream>>>(z, hW0, hb0, h0T);
    gemmT_kernel<<<256, 512, 0, stream>>>(h0T, hW1, hb1, h1T);
    gemmT_kernel<<<256, 512, 0, stream>>>(h1T, hW2, hb2, h2T);
    wabT_kernel<<<536, 256, 0, stream>>>(h2T, hWo, hbo, wab);
    decoder_kernel<<<256, 256, 0, stream>>>(wab, logP, out);
}

// Round 8
// 101.574 us; speedup vs baseline: 1.0564x; 1.0564x over previous
//
#include <hip/hip_runtime.h>

#define WSTRIDE 8704   // padded row stride for wab (shifted layout, max idx 8452)

__device__ __forceinline__ float lrelu(float x) { return x > 0.0f ? x : 0.01f * x; }

// h0T[j][b] = lrelu(sum_l z[b][l]*W0[l][j] + b0[j]); one block per j, lane = b
__global__ __launch_bounds__(128) void h0T_kernel(const float* __restrict__ z,
                                                  const float* __restrict__ W,
                                                  const float* __restrict__ bias,
                                                  float* __restrict__ h0T) {
    int j = blockIdx.x;          // 0..511
    int b = threadIdx.x;         // 0..127
    float zr[16];
    *(float4*)&zr[0]  = *(const float4*)&z[b * 16 + 0];
    *(float4*)&zr[4]  = *(const float4*)&z[b * 16 + 4];
    *(float4*)&zr[8]  = *(const float4*)&z[b * 16 + 8];
    *(float4*)&zr[12] = *(const float4*)&z[b * 16 + 12];
    float acc = bias[j];
#pragma unroll
    for (int l = 0; l < 16; ++l) acc = fmaf(zr[l], W[l * 512 + j], acc);
    h0T[j * 128 + b] = lrelu(acc);
}

// OT[j][b] = lrelu(sum_k At[k][b]*W[k][j] + bias[j]); At is [512][128]
// lane owns jl=8 j's (aligned float4 W loads), bb=2 b's; 8 k-split waves;
// A broadcast from LDS (b64); parallel per-wave partials + single reduce pass.
__global__ __launch_bounds__(512) void gemmT_kernel(const float* __restrict__ At,
                                                    const float* __restrict__ W,
                                                    const float* __restrict__ bias,
                                                    float* __restrict__ OT) {
    __shared__ __align__(16) float2 As2[512];       // 4 KB
    __shared__ __align__(16) float red[8][2][520];  // 33.3 KB
    int tid = threadIdx.x;
    int lane = tid & 63;
    int wid = __builtin_amdgcn_readfirstlane(tid >> 6);  // 0..7
    int b0 = blockIdx.x * 2;                             // 0..126
    As2[tid] = *(const float2*)&At[tid * 128 + b0];      // k = tid
    __syncthreads();
    int j0 = lane * 8;
    int k0 = wid * 64;
    float acc[2][8];
#pragma unroll
    for (int e = 0; e < 8; ++e) { acc[0][e] = 0.f; acc[1][e] = 0.f; }
#pragma unroll 4
    for (int kk = 0; kk < 64; ++kk) {
        int k = k0 + kk;
        float2 a = As2[k];                               // LDS broadcast (b64)
        const float* wr = W + (size_t)k * 512 + j0;      // 16B aligned
        float4 wA = *(const float4*)&wr[0];
        float4 wB = *(const float4*)&wr[4];
        float wv[8] = {wA.x, wA.y, wA.z, wA.w, wB.x, wB.y, wB.z, wB.w};
#pragma unroll
        for (int e = 0; e < 8; ++e) {
            acc[0][e] = fmaf(a.x, wv[e], acc[0][e]);
            acc[1][e] = fmaf(a.y, wv[e], acc[1][e]);
        }
    }
    *(float4*)&red[wid][0][j0]     = make_float4(acc[0][0], acc[0][1], acc[0][2], acc[0][3]);
    *(float4*)&red[wid][0][j0 + 4] = make_float4(acc[0][4], acc[0][5], acc[0][6], acc[0][7]);
    *(float4*)&red[wid][1][j0]     = make_float4(acc[1][0], acc[1][1], acc[1][2], acc[1][3]);
    *(float4*)&red[wid][1][j0 + 4] = make_float4(acc[1][4], acc[1][5], acc[1][6], acc[1][7]);
    __syncthreads();
    int j = tid;                                         // 0..511
    float s0 = 0.f, s1 = 0.f;
#pragma unroll
    for (int w = 0; w < 8; ++w) { s0 += red[w][0][j]; s1 += red[w][1][j]; }
    float bj = bias[j];
    OT[j * 128 + b0 + 0] = lrelu(s0 + bj);
    OT[j * 128 + b0 + 1] = lrelu(s1 + bj);
}

// wab[b][dest(j)] = sum_k At[k][b]*hWo[k][j] + hbo[j]; dest(j)=j+(j>=65?3:0)
// Per-lane tile: bb=8 (A via LDS b128 broadcast) x jl=8 (W via 4x float2).
// 4 k-split waves, acc[8][8]=64 VGPR, 4-stage named-struct register pipeline.
// Grid 272 = 17 jt (512 j) x 16 bt (8 b), XCD-grouped. jt=16 tail: clamped
// loads at j0=8442, remapped store indices.
struct St { float4 aL, aH; float2 w0, w1, w2, w3; };

__global__ __launch_bounds__(256, 2) void wabT_kernel(const float* __restrict__ At,
                                                      const float* __restrict__ W,
                                                      const float* __restrict__ bias,
                                                      float* __restrict__ wab) {
    __shared__ __align__(16) float As[512][8];    // 16 KB
    __shared__ __align__(16) float red[8][520];   // 16.6 KB: red[b][j-local]
    int tid = threadIdx.x;
    int lane = tid & 63;
    int wid = __builtin_amdgcn_readfirstlane(tid >> 6);  // 0..3
    int v = (blockIdx.x & 7) * 34 + (blockIdx.x >> 3);   // 0..271 XCD-grouped
    int jt = v >> 4;                   // 0..16
    int bt = v & 15;                   // 0..15
    int b0 = bt * 8;
    // stage At[:, b0:b0+8] -> As (16 float4 per thread)
#pragma unroll
    for (int r = 0; r < 4; ++r) {
        int p = r * 256 + tid;         // 0..1023
        int k = p >> 1, h = p & 1;
        *(float4*)&As[k][h * 4] = *(const float4*)&At[k * 128 + b0 + h * 4];
    }
    __syncthreads();

    int j0r = jt * 512 + lane * 8;
    int j0 = j0r <= 8442 ? j0r : 8442;     // clamp (even -> 8B-aligned float2s)
    int k0 = wid * 128;
    const float* __restrict__ Wp = W + (size_t)k0 * 8450 + j0;
    float acc[8][8];
#pragma unroll
    for (int i = 0; i < 8; ++i)
#pragma unroll
        for (int j = 0; j < 8; ++j) acc[i][j] = 0.f;

#define LD(S, kk) do {                                          \
        S.aL = *(const float4*)&As[k0 + (kk)][0];               \
        S.aH = *(const float4*)&As[k0 + (kk)][4];               \
        const float* wr_ = Wp + (size_t)(kk) * 8450;            \
        S.w0 = *(const float2*)(wr_ + 0);                       \
        S.w1 = *(const float2*)(wr_ + 2);                       \
        S.w2 = *(const float2*)(wr_ + 4);                       \
        S.w3 = *(const float2*)(wr_ + 6);                       \
    } while (0)
#define FM(S) do {                                              \
        float av_[8] = {S.aL.x, S.aL.y, S.aL.z, S.aL.w,         \
                        S.aH.x, S.aH.y, S.aH.z, S.aH.w};        \
        float wv_[8] = {S.w0.x, S.w0.y, S.w1.x, S.w1.y,         \
                        S.w2.x, S.w2.y, S.w3.x, S.w3.y};        \
        _Pragma("unroll")                                       \
        for (int i_ = 0; i_ < 8; ++i_)                          \
            _Pragma("unroll")                                   \
            for (int j_ = 0; j_ < 8; ++j_)                      \
                acc[i_][j_] = fmaf(av_[i_], wv_[j_], acc[i_][j_]); \
    } while (0)

    St s0, s1, s2, s3;
    LD(s0, 0); LD(s1, 1); LD(s2, 2);
    for (int kk = 0; kk < 124; kk += 4) {
        LD(s3, kk + 3); FM(s0);
        LD(s0, kk + 4); FM(s1);
        LD(s1, kk + 5); FM(s2);
        LD(s2, kk + 6); FM(s3);
    }
    LD(s3, 127); FM(s0); FM(s1); FM(s2); FM(s3);
#undef LD
#undef FM

    int jl = lane * 8;
    if (wid == 0) {
#pragma unroll
        for (int b = 0; b < 8; ++b) {
            *(float4*)&red[b][jl]     = make_float4(acc[b][0], acc[b][1], acc[b][2], acc[b][3]);
            *(float4*)&red[b][jl + 4] = make_float4(acc[b][4], acc[b][5], acc[b][6], acc[b][7]);
        }
    }
    __syncthreads();
#pragma unroll
    for (int w = 1; w < 4; ++w) {
        if (wid == w) {
#pragma unroll
            for (int b = 0; b < 8; ++b) {
                float4 e0 = *(float4*)&red[b][jl];
                float4 e1 = *(float4*)&red[b][jl + 4];
                e0.x += acc[b][0]; e0.y += acc[b][1]; e0.z += acc[b][2]; e0.w += acc[b][3];
                e1.x += acc[b][4]; e1.y += acc[b][5]; e1.z += acc[b][6]; e1.w += acc[b][7];
                *(float4*)&red[b][jl]     = e0;
                *(float4*)&red[b][jl + 4] = e1;
            }
        }
        __syncthreads();
    }
    // final: thread t -> b = t&7, 16 consecutive j-locals
    int bb = tid & 7;
    int jl0 = (tid >> 3) * 16;
    float* drow = wab + (size_t)(b0 + bb) * WSTRIDE;
#pragma unroll
    for (int r = 0; r < 16; ++r) {
        int rg = jl0 + r;
        int jg = jt * 512 + rg;
        if (jt == 16 && rg >= 256) jg = 8442 + (rg - 256);  // tail remap (dup-writes benign)
        if (jg < 8450) {
            float sres = red[bb][rg] + bias[jg];
            drow[jg + (jg >= 65 ? 3 : 0)] = sres;
        }
    }
}

// Decoder. wab row (shifted): w0[0:64], b0[64], pad[65:68), W1[68:4164),
// b1[4164:4228), W2[4228:8324), b2[8324:8388), w3[8388:8452), b3[8452].
// One block per b: 8 waves = 2 g-halves x 4 j-quarters; h state [j][128g] in LDS;
// W via uniform-address VMEM float4 broadcasts (jq kept on vector path).
__global__ __launch_bounds__(512) void decoder_kernel(const float* __restrict__ wab,
                                                      const float* __restrict__ logP,
                                                      float* __restrict__ out) {
    __shared__ float hX[64 * 130];     // 33.3 KB
    __shared__ float hY[64 * 130];
    __shared__ float red[4][132];
    int b = blockIdx.x;                // 0..127
    int tid = threadIdx.x;
    int lane = tid & 63;
    int gh = (tid >> 6) & 1;
    int jq = (tid >> 7) * 16;          // 0,16,32,48 (vector path, not readfirstlane)
    int gcol = gh * 64 + lane;         // == g
    bool act = gcol < 100;
    const float* __restrict__ row = wab + (size_t)b * WSTRIDE;
    float x0 = act ? logP[b * 100 + gcol] * (1.0f / 3.0f) : 0.0f;
    float c0 = row[64];
#pragma unroll
    for (int t = 0; t < 16; ++t)
        hX[(jq + t) * 130 + gcol] = __sinf(30.0f * fmaf(x0, row[jq + t], c0));
    __syncthreads();
    // layer 1
    {
        float a[16];
#pragma unroll
        for (int t = 0; t < 16; ++t) a[t] = row[4164 + jq + t];
#pragma unroll 4
        for (int i = 0; i < 64; ++i) {
            float hi = hX[i * 130 + gcol];
            const float* wr = row + 68 + i * 64 + jq;   // 16B aligned
            float4 w0 = *(const float4*)&wr[0];
            float4 w1 = *(const float4*)&wr[4];
            float4 w2 = *(const float4*)&wr[8];
            float4 w3 = *(const float4*)&wr[12];
            a[0]  = fmaf(hi, w0.x, a[0]);  a[1]  = fmaf(hi, w0.y, a[1]);
            a[2]  = fmaf(hi, w0.z, a[2]);  a[3]  = fmaf(hi, w0.w, a[3]);
            a[4]  = fmaf(hi, w1.x, a[4]);  a[5]  = fmaf(hi, w1.y, a[5]);
            a[6]  = fmaf(hi, w1.z, a[6]);  a[7]  = fmaf(hi, w1.w, a[7]);
            a[8]  = fmaf(hi, w2.x, a[8]);  a[9]  = fmaf(hi, w2.y, a[9]);
            a[10] = fmaf(hi, w2.z, a[10]); a[11] = fmaf(hi, w2.w, a[11]);
            a[12] = fmaf(hi, w3.x, a[12]); a[13] = fmaf(hi, w3.y, a[13]);
            a[14] = fmaf(hi, w3.z, a[14]); a[15] = fmaf(hi, w3.w, a[15]);
        }
#pragma unroll
        for (int t = 0; t < 16; ++t) hY[(jq + t) * 130 + gcol] = __sinf(a[t]);
    }
    __syncthreads();
    // layer 2
    {
        float a[16];
#pragma unroll
        for (int t = 0; t < 16; ++t) a[t] = row[8324 + jq + t];
#pragma unroll 4
        for (int i = 0; i < 64; ++i) {
            float hi = hY[i * 130 + gcol];
            const float* wr = row + 4228 + i * 64 + jq;
            float4 w0 = *(const float4*)&wr[0];
            float4 w1 = *(const float4*)&wr[4];
            float4 w2 = *(const float4*)&wr[8];
            float4 w3 = *(const float4*)&wr[12];
            a[0]  = fmaf(hi, w0.x, a[0]);  a[1]  = fmaf(hi, w0.y, a[1]);
            a[2]  = fmaf(hi, w0.z, a[2]);  a[3]  = fmaf(hi, w0.w, a[3]);
            a[4]  = fmaf(hi, w1.x, a[4]);  a[5]  = fmaf(hi, w1.y, a[5]);
            a[6]  = fmaf(hi, w1.z, a[6]);  a[7]  = fmaf(hi, w1.w, a[7]);
            a[8]  = fmaf(hi, w2.x, a[8]);  a[9]  = fmaf(hi, w2.y, a[9]);
            a[10] = fmaf(hi, w2.z, a[10]); a[11] = fmaf(hi, w2.w, a[11]);
            a[12] = fmaf(hi, w3.x, a[12]); a[13] = fmaf(hi, w3.y, a[13]);
            a[14] = fmaf(hi, w3.z, a[14]); a[15] = fmaf(hi, w3.w, a[15]);
        }
#pragma unroll
        for (int t = 0; t < 16; ++t) hX[(jq + t) * 130 + gcol] = __sinf(a[t]);
    }
    __syncthreads();
    // layer 3
    float p = 0.f;
#pragma unroll
    for (int t = 0; t < 16; ++t)
        p = fmaf(hX[(jq + t) * 130 + gcol], row[8388 + jq + t], p);
    red[tid >> 7][gcol] = p;
    __syncthreads();
    if (tid < 128 && act) {
        float s = red[0][gcol] + red[1][gcol] + red[2][gcol] + red[3][gcol] + row[8452];
        out[b * 100 + gcol] = fmaf(s, 500.0f, 1500.0f);
    }
}

extern "C" void kernel_launch(void* const* d_in, const int* in_sizes, int n_in,
                              void* d_out, int out_size, void* d_ws, size_t ws_size,
                              hipStream_t stream) {
    const float* z    = (const float*)d_in[0];
    const float* logP = (const float*)d_in[1];
    const float* hW0  = (const float*)d_in[2];
    const float* hb0  = (const float*)d_in[3];
    const float* hW1  = (const float*)d_in[4];
    const float* hb1  = (const float*)d_in[5];
    const float* hW2  = (const float*)d_in[6];
    const float* hb2  = (const float*)d_in[7];
    const float* hWo  = (const float*)d_in[8];
    const float* hbo  = (const float*)d_in[9];
    float* out = (float*)d_out;

    float* wab = (float*)d_ws;               // 128*8704 floats (4.46 MB)
    float* h0T = wab + 128 * WSTRIDE;        // 512*128 floats (transposed)
    float* h1T = h0T + 512 * 128;
    float* h2T = h1T + 512 * 128;            // total ~5.25 MB

    h0T_kernel<<<512, 128, 0, stream>>>(z, hW0, hb0, h0T);
    gemmT_kernel<<<64, 512, 0, stream>>>(h0T, hW1, hb1, h1T);
    gemmT_kernel<<<64, 512, 0, stream>>>(h1T, hW2, hb2, h2T);
    wabT_kernel<<<272, 256, 0, stream>>>(h2T, hWo, hbo, wab);
    decoder_kernel<<<128, 512, 0, stream>>>(wab, logP, out);
}

// Round 9
// 69.177 us; speedup vs baseline: 1.5512x; 1.4683x over previous
//
#include <hip/hip_runtime.h>

#define WSTRIDE 8704   // padded row stride for wab (shifted layout, max idx 8452)

__device__ __forceinline__ float lrelu(float x) { return x > 0.0f ? x : 0.01f * x; }

// h0T[j][b] = lrelu(sum_l z[b][l]*W0[l][j] + b0[j]); one block per j, lane = b
__global__ __launch_bounds__(128) void h0T_kernel(const float* __restrict__ z,
                                                  const float* __restrict__ W,
                                                  const float* __restrict__ bias,
                                                  float* __restrict__ h0T) {
    int j = blockIdx.x;          // 0..511
    int b = threadIdx.x;         // 0..127
    float zr[16];
    *(float4*)&zr[0]  = *(const float4*)&z[b * 16 + 0];
    *(float4*)&zr[4]  = *(const float4*)&z[b * 16 + 4];
    *(float4*)&zr[8]  = *(const float4*)&z[b * 16 + 8];
    *(float4*)&zr[12] = *(const float4*)&z[b * 16 + 12];
    float acc = bias[j];
#pragma unroll
    for (int l = 0; l < 16; ++l) acc = fmaf(zr[l], W[l * 512 + j], acc);
    h0T[j * 128 + b] = lrelu(acc);
}

// OT[j][b] = lrelu(sum_k At[k][b]*W[k][j] + bias[j])  — R5-proven config.
// tile 64 j x 4 b, k-split 8 (512 thr); grid 256 = 8 jt x 32 bt (1 block/CU, 8 waves).
__global__ __launch_bounds__(512) void gemmT_kernel(const float* __restrict__ At,
                                                    const float* __restrict__ W,
                                                    const float* __restrict__ bias,
                                                    float* __restrict__ OT) {
    __shared__ __align__(16) float As[512][4];   // 8 KB
    __shared__ float red[8][64][5];              // 10 KB
    int jt = blockIdx.x & 7;
    int bt = blockIdx.x >> 3;          // 0..31
    int tid = threadIdx.x;
    int lane = tid & 63;
    int wid  = __builtin_amdgcn_readfirstlane(tid >> 6);  // 0..7
    int b0 = bt * 4;
#pragma unroll
    for (int r = 0; r < 2; ++r) {
        int p = r * 512 + tid;
        int k = p >> 1, q = p & 1;
        *(float2*)&As[k][q * 2] = *(const float2*)&At[k * 128 + b0 + q * 2];
    }
    __syncthreads();
    int j = jt * 64 + lane;
    float acc[4] = {};
    int k0 = wid * 64;
#pragma unroll 8
    for (int kk = 0; kk < 64; ++kk) {
        int k = k0 + kk;
        float4 a = *(const float4*)&As[k][0];   // LDS broadcast
        float w = W[k * 512 + j];               // coalesced dword
        acc[0] = fmaf(a.x, w, acc[0]);
        acc[1] = fmaf(a.y, w, acc[1]);
        acc[2] = fmaf(a.z, w, acc[2]);
        acc[3] = fmaf(a.w, w, acc[3]);
    }
#pragma unroll
    for (int i = 0; i < 4; ++i) red[wid][lane][i] = acc[i];
    __syncthreads();
    if (tid < 256) {
        int jj = tid >> 2;
        int bb = tid & 3;
        float s = 0.f;
#pragma unroll
        for (int w = 0; w < 8; ++w) s += red[w][jj][bb];
        int jg = jt * 64 + jj;
        OT[jg * 128 + b0 + bb] = lrelu(s + bias[jg]);
    }
}

// wab[b][dest(j)] = sum_k At[k][b]*hWo[k][j] + hbo[j]; dest(j)=j+(j>=65?3:0)
// Tile 128 j x 8 b x ks4 (256 thr). Per-lane bb=8, jl=2, acc=16 regs — no manual
// pipeline (TLP from 4.25 blocks/CU hides latency). Grid 1088 = 68 jt x 16 bt;
// consecutive blocks = 16 bt of one jt spread round-robin over the 8 XCDs.
// LDS: As[512][8] (16 KB) reused as the reduce buffer after the k-loop.
__global__ __launch_bounds__(256) void wabT_kernel(const float* __restrict__ At,
                                                   const float* __restrict__ W,
                                                   const float* __restrict__ bias,
                                                   float* __restrict__ wab) {
    __shared__ __align__(16) float smem[4352];   // max(As 4096, red 4224)
    float (*As)[8] = (float (*)[8])smem;
    int tid = threadIdx.x;
    int lane = tid & 63;
    int wid = __builtin_amdgcn_readfirstlane(tid >> 6);  // 0..3
    int jt = blockIdx.x >> 4;          // 0..67
    int bt = blockIdx.x & 15;          // 0..15
    if (jt >= 67) return;              // jt 67 entirely past j=8449
    int b0 = bt * 8;
    // stage At[0:512][b0:b0+8] -> As (float4)
#pragma unroll
    for (int r = 0; r < 8; ++r) {
        int p = r * 256 + tid;         // 0..2047
        int k = p >> 1, h = (p & 1) * 4;
        *(float4*)&As[k][h] = *(const float4*)&At[k * 128 + b0 + h];
    }
    __syncthreads();
    int j0r = jt * 128 + lane * 2;
    int j0 = j0r <= 8448 ? j0r : 8448; // clamp (even -> 8B-aligned float2)
    int k0 = wid * 128;
    const float* __restrict__ Wp = W + (size_t)k0 * 8450 + j0;
    float acc[8][2];
#pragma unroll
    for (int i = 0; i < 8; ++i) { acc[i][0] = 0.f; acc[i][1] = 0.f; }
#pragma unroll 4
    for (int kk = 0; kk < 128; ++kk) {
        float4 aL = *(const float4*)&As[k0 + kk][0];   // LDS broadcast
        float4 aH = *(const float4*)&As[k0 + kk][4];
        float2 w = *(const float2*)(Wp + (size_t)kk * 8450);
        float av[8] = {aL.x, aL.y, aL.z, aL.w, aH.x, aH.y, aH.z, aH.w};
#pragma unroll
        for (int i = 0; i < 8; ++i) {
            acc[i][0] = fmaf(av[i], w.x, acc[i][0]);
            acc[i][1] = fmaf(av[i], w.y, acc[i][1]);
        }
    }
    __syncthreads();                   // As dead; reuse smem as red[(w*8+b)*132 + j]
#pragma unroll
    for (int i = 0; i < 8; ++i) {
        smem[(wid * 8 + i) * 132 + lane * 2 + 0] = acc[i][0];
        smem[(wid * 8 + i) * 132 + lane * 2 + 1] = acc[i][1];
    }
    __syncthreads();
    int j = tid & 127;
    int bs = tid >> 7;                 // 0..1 -> 4 b's each
    int jg = jt * 128 + j;
    if (jg < 8450) {
        float bj = bias[jg];
        int dst = jg + (jg >= 65 ? 3 : 0);
#pragma unroll
        for (int q = 0; q < 4; ++q) {
            int bb = bs * 4 + q;
            float s = smem[(0 * 8 + bb) * 132 + j] + smem[(1 * 8 + bb) * 132 + j]
                    + smem[(2 * 8 + bb) * 132 + j] + smem[(3 * 8 + bb) * 132 + j];
            wab[(size_t)(b0 + bb) * WSTRIDE + dst] = s + bj;
        }
    }
}

// Decoder. wab row (shifted): w0[0:64], b0[64], pad[65:68), W1[68:4164),
// b1[4164:4228), W2[4228:8324), b2[8324:8388), w3[8388:8452), b3[8452].
// Grid 256 = (b, g-half); 512 thr = 8 waves, wave owns 8 j. lane = g.
// W via uniform-address VMEM float4 broadcasts (jq on vector path).
__global__ __launch_bounds__(512) void decoder_kernel(const float* __restrict__ wab,
                                                      const float* __restrict__ logP,
                                                      float* __restrict__ out) {
    __shared__ float hX[64 * 65];      // 16.6 KB, h[j][g]
    __shared__ float hY[64 * 65];
    __shared__ float red[8][68];
    int b  = blockIdx.x >> 1;
    int gh = blockIdx.x & 1;
    int tid = threadIdx.x;
    int lane = tid & 63;
    int jq = (tid >> 6) * 8;           // 0..56, vector path (no readfirstlane)
    int g = gh * 64 + lane;
    bool act = g < 100;
    const float* __restrict__ row = wab + (size_t)b * WSTRIDE;
    float x0 = act ? logP[b * 100 + g] * (1.0f / 3.0f) : 0.0f;
    float c0 = row[64];
#pragma unroll
    for (int t = 0; t < 8; ++t)
        hX[(jq + t) * 65 + lane] = __sinf(30.0f * fmaf(x0, row[jq + t], c0));
    __syncthreads();
    // layer 1: hY[j][g] = sin(sum_i hX[i][g]*W1[i][j] + b1[j])
    {
        float a[8];
#pragma unroll
        for (int t = 0; t < 8; ++t) a[t] = row[4164 + jq + t];
#pragma unroll 4
        for (int i = 0; i < 64; ++i) {
            float hi = hX[i * 65 + lane];
            const float* wr = row + 68 + i * 64 + jq;   // 16B aligned
            float4 w0 = *(const float4*)&wr[0];
            float4 w1 = *(const float4*)&wr[4];
            a[0] = fmaf(hi, w0.x, a[0]);  a[1] = fmaf(hi, w0.y, a[1]);
            a[2] = fmaf(hi, w0.z, a[2]);  a[3] = fmaf(hi, w0.w, a[3]);
            a[4] = fmaf(hi, w1.x, a[4]);  a[5] = fmaf(hi, w1.y, a[5]);
            a[6] = fmaf(hi, w1.z, a[6]);  a[7] = fmaf(hi, w1.w, a[7]);
        }
#pragma unroll
        for (int t = 0; t < 8; ++t) hY[(jq + t) * 65 + lane] = __sinf(a[t]);
    }
    __syncthreads();
    // layer 2: hX[j][g] = sin(sum_i hY[i][g]*W2[i][j] + b2[j])
    {
        float a[8];
#pragma unroll
        for (int t = 0; t < 8; ++t) a[t] = row[8324 + jq + t];
#pragma unroll 4
        for (int i = 0; i < 64; ++i) {
            float hi = hY[i * 65 + lane];
            const float* wr = row + 4228 + i * 64 + jq;
            float4 w0 = *(const float4*)&wr[0];
            float4 w1 = *(const float4*)&wr[4];
            a[0] = fmaf(hi, w0.x, a[0]);  a[1] = fmaf(hi, w0.y, a[1]);
            a[2] = fmaf(hi, w0.z, a[2]);  a[3] = fmaf(hi, w0.w, a[3]);
            a[4] = fmaf(hi, w1.x, a[4]);  a[5] = fmaf(hi, w1.y, a[5]);
            a[6] = fmaf(hi, w1.z, a[6]);  a[7] = fmaf(hi, w1.w, a[7]);
        }
#pragma unroll
        for (int t = 0; t < 8; ++t) hX[(jq + t) * 65 + lane] = __sinf(a[t]);
    }
    __syncthreads();
    // layer 3: partial dot over this wave's 8 j's, cross-wave reduce
    float p = 0.f;
#pragma unroll
    for (int t = 0; t < 8; ++t)
        p = fmaf(hX[(jq + t) * 65 + lane], row[8388 + jq + t], p);
    red[tid >> 6][lane] = p;
    __syncthreads();
    if (tid < 64 && act) {
        float s = row[8452];
#pragma unroll
        for (int w = 0; w < 8; ++w) s += red[w][lane];
        out[b * 100 + g] = fmaf(s, 500.0f, 1500.0f);
    }
}

extern "C" void kernel_launch(void* const* d_in, const int* in_sizes, int n_in,
                              void* d_out, int out_size, void* d_ws, size_t ws_size,
                              hipStream_t stream) {
    const float* z    = (const float*)d_in[0];
    const float* logP = (const float*)d_in[1];
    const float* hW0  = (const float*)d_in[2];
    const float* hb0  = (const float*)d_in[3];
    const float* hW1  = (const float*)d_in[4];
    const float* hb1  = (const float*)d_in[5];
    const float* hW2  = (const float*)d_in[6];
    const float* hb2  = (const float*)d_in[7];
    const float* hWo  = (const float*)d_in[8];
    const float* hbo  = (const float*)d_in[9];
    float* out = (float*)d_out;

    float* wab = (float*)d_ws;               // 128*8704 floats (4.46 MB)
    float* h0T = wab + 128 * WSTRIDE;        // 512*128 floats (transposed)
    float* h1T = h0T + 512 * 128;
    float* h2T = h1T + 512 * 128;            // total ~5.25 MB

    h0T_kernel<<<512, 128, 0, stream>>>(z, hW0, hb0, h0T);
    gemmT_kernel<<<256, 512, 0, stream>>>(h0T, hW1, hb1, h1T);
    gemmT_kernel<<<256, 512, 0, stream>>>(h1T, hW2, hb2, h2T);
    wabT_kernel<<<1088, 256, 0, stream>>>(h2T, hWo, hbo, wab);
    decoder_kernel<<<256, 512, 0, stream>>>(wab, logP, out);
}